// Round 1
// baseline (217.625 us; speedup 1.0000x reference)
//
#include <hip/hip_runtime.h>

#define N_NODES 50000
#define N_EDGES 800000
#define D_FEAT 64

// Phase 1: out-degree histogram. deg[u] = # edges with src == u.
__global__ void sgc_degree_kernel(const int* __restrict__ src,
                                  unsigned int* __restrict__ deg,
                                  int n_edges) {
    int i = blockIdx.x * blockDim.x + threadIdx.x;
    int stride = gridDim.x * blockDim.x;
    for (; i < n_edges; i += stride) {
        atomicAdd(&deg[src[i]], 1u);
    }
}

// Phase 2: per-edge gather-scale-scatter. One wave per edge; lane = feature.
__global__ void sgc_scatter_kernel(const float* __restrict__ x,
                                   const int* __restrict__ src,
                                   const int* __restrict__ dst,
                                   const unsigned int* __restrict__ deg,
                                   float* __restrict__ h,
                                   int n_edges) {
    const int lane = threadIdx.x & 63;
    const int wave = (int)((blockIdx.x * blockDim.x + threadIdx.x) >> 6);
    const int nwaves = (int)((gridDim.x * blockDim.x) >> 6);

    for (int e = wave; e < n_edges; e += nwaves) {
        // Wave-uniform edge metadata; make uniformity explicit for SALU use.
        int s = __builtin_amdgcn_readfirstlane(src[e]);
        int d = __builtin_amdgcn_readfirstlane(dst[e]);
        float ds = (float)deg[s];
        float dd = (float)deg[d];
        float norm = rsqrtf(ds * dd);   // matches 1/sqrt(deg_u*deg_v) within fp tolerance

        float v = x[s * D_FEAT + lane] * norm;   // coalesced 256B row read
        atomicAdd(&h[d * D_FEAT + lane], v);     // device-scope f32 atomic
    }
}

extern "C" void kernel_launch(void* const* d_in, const int* in_sizes, int n_in,
                              void* d_out, int out_size, void* d_ws, size_t ws_size,
                              hipStream_t stream) {
    const float* x   = (const float*)d_in[0];
    const int*   src = (const int*)d_in[1];
    const int*   dst = (const int*)d_in[2];
    float* h = (float*)d_out;

    const int n_edges = in_sizes[1];

    unsigned int* deg = (unsigned int*)d_ws;  // 50000 u32 = 200 KB

    // Zero accumulators (harness poisons d_out/d_ws with 0xAA).
    hipMemsetAsync(deg, 0, N_NODES * sizeof(unsigned int), stream);
    hipMemsetAsync(d_out, 0, (size_t)out_size * sizeof(float), stream);

    // Degree histogram.
    {
        dim3 block(256);
        dim3 grid(1024);
        sgc_degree_kernel<<<grid, block, 0, stream>>>(src, deg, n_edges);
    }

    // Gather-scale-scatter: one wave per edge, grid-stride.
    {
        dim3 block(256);
        dim3 grid(2048);  // 8192 waves = 256 CU * 32 waves
        sgc_scatter_kernel<<<grid, block, 0, stream>>>(x, src, dst, deg, h, n_edges);
    }
}